// Round 4
// baseline (1177.813 us; speedup 1.0000x reference)
//
#include <hip/hip_runtime.h>
#include <hip/hip_bf16.h>

// GCN 2-layer: N=100000, E=3200000, F 512->16->40, fp32 in/out.
// Pipeline (5 dispatches), CSR-FREE:
//   zero(deg+cursor) -> binsort (hist -> slot-reserve -> direct scattered
//   write, deg fused) -> GEMM1 (W-in-regs, rsqrt(deg) scale, bf16 out) ->
//   agg1: per-bucket LDS fp32 accumulate over binned edges (+self+bias+relu,
//   bf16 out) -> agg2: same accumulate + W2 + b2 + log_softmax.
// No CSR build, no gather kernels: aggregation is a streaming, coalesced
// pass over binned edges with ds_add_f32 into a 128x16 LDS accumulator.
// bf16 tables (3.2MB) stay L2-resident.

#define NF0 512
#define NF1 16
#define NF2 40
#define BSHIFT 7            // 128 nodes per bucket
#define BNODES 128
#define MAXPB 5120          // slots per bucket; mean 4096, sigma 64 -> +16 sigma

// bf16 pair helpers: uint u = bf16(lo) | bf16(hi)<<16
__device__ __forceinline__ float bflo(unsigned int u) { return __uint_as_float(u << 16); }
__device__ __forceinline__ float bfhi(unsigned int u) { return __uint_as_float(u & 0xFFFF0000u); }
__device__ __forceinline__ unsigned int packbf(float lo, float hi) {
    unsigned int bl = __float_as_uint(lo);
    bl = (bl + 0x7FFFu + ((bl >> 16) & 1u)) >> 16;
    unsigned int bh = __float_as_uint(hi);
    bh = (bh + 0x7FFFu + ((bh >> 16) & 1u)) & 0xFFFF0000u;
    return bl | bh;
}

// LDS float atomic add, no return value -> ds_add_f32
__device__ __forceinline__ void ldsAdd(float* p, float v) {
    __hip_atomic_fetch_add(p, v, __ATOMIC_RELAXED, __HIP_MEMORY_SCOPE_WORKGROUP);
}

// ---------------- zero deg + cursors ----------------

__global__ void k_zero(int* __restrict__ p, int n) {
    int i = blockIdx.x * 256 + threadIdx.x;
    if (i < n) p[i] = 0;
}

// ---------------- binsort: hist -> reserve -> direct scattered write ----------------
// Slotted layout binned[b*MAXPB + slot]; cursor[b] ends as bucket count.
// deg[dst]++ fused into the write pass.

__global__ __launch_bounds__(256) void k_binsort(
    const int* __restrict__ src, const int* __restrict__ dst,
    int* __restrict__ cursor, int* __restrict__ deg,
    unsigned int* __restrict__ binned, int E, int NB, int chunkSz) {
    extern __shared__ int dyn[];
    int* hist = dyn;          // NB (reused as local placement cursor)
    int* gbase = dyn + NB;    // NB

    const int t = threadIdx.x;
    const int base = blockIdx.x * chunkSz;
    const int ne = min(chunkSz, E - base);

    for (int i = t; i < NB; i += 256) hist[i] = 0;
    __syncthreads();

    for (int i = t; i < ne; i += 256)
        atomicAdd(&hist[dst[base + i] >> BSHIFT], 1);
    __syncthreads();

    for (int b = t; b < NB; b += 256) {
        int c = hist[b];
        if (c > 0) gbase[b] = b * MAXPB + atomicAdd(&cursor[b], c);
        hist[b] = 0;
    }
    __syncthreads();

    for (int i = t; i < ne; i += 256) {
        int d = dst[base + i];
        int s = src[base + i];
        int b = d >> BSHIFT;
        int pos = atomicAdd(&hist[b], 1);
        binned[gbase[b] + pos] =
            ((unsigned int)(d & (BNODES - 1)) << 20) | (unsigned int)s;
        atomicAdd(&deg[d], 1);
    }
}

// ---------------- GEMM1: h1s[n][c] = bf16( dinv[n] * sum_k x[n][k]*W1[k][c] ) ----------
// One wave per row, barrier-free; W1 in 128 VGPRs; shuffle-butterfly reduce;
// 2-deep row prefetch. dinv = rsqrt(deg+1) inline. Output packed bf16 pairs.

__global__ __launch_bounds__(256, 2) void k_gemm1(
    const float* __restrict__ x, const float* __restrict__ W1,
    const int* __restrict__ deg, unsigned int* __restrict__ h1s, int n) {
    const int lane = threadIdx.x & 63;
    const int wav = threadIdx.x >> 6;

    float wA[4][16], wB[4][16];
    const float4* W1v = (const float4*)W1;
    #pragma unroll
    for (int j = 0; j < 4; ++j) {
        #pragma unroll
        for (int q = 0; q < 4; ++q) {
            float4 wa = W1v[(4 * lane + j) * 4 + q];
            wA[j][4 * q + 0] = wa.x; wA[j][4 * q + 1] = wa.y;
            wA[j][4 * q + 2] = wa.z; wA[j][4 * q + 3] = wa.w;
            float4 wb = W1v[(256 + 4 * lane + j) * 4 + q];
            wB[j][4 * q + 0] = wb.x; wB[j][4 * q + 1] = wb.y;
            wB[j][4 * q + 2] = wb.z; wB[j][4 * q + 3] = wb.w;
        }
    }

    const float4* xv = (const float4*)x;
    const int stride = gridDim.x * 4;

    auto process = [&](float4 p0, float4 p1, int r) {
        float part[16];
        #pragma unroll
        for (int c = 0; c < 16; ++c) part[c] = 0.f;
        float av[8] = {p0.x, p0.y, p0.z, p0.w, p1.x, p1.y, p1.z, p1.w};
        #pragma unroll
        for (int j = 0; j < 4; ++j) {
            #pragma unroll
            for (int c = 0; c < 16; ++c) {
                part[c] = fmaf(av[j], wA[j][c], part[c]);
                part[c] = fmaf(av[4 + j], wB[j][c], part[c]);
            }
        }
        const bool h5 = (lane & 32) != 0;
        float v8[8];
        #pragma unroll
        for (int j = 0; j < 8; ++j)
            v8[j] = (h5 ? part[j + 8] : part[j]) +
                    __shfl_xor(h5 ? part[j] : part[j + 8], 32, 64);
        const bool h4 = (lane & 16) != 0;
        float v4[4];
        #pragma unroll
        for (int j = 0; j < 4; ++j)
            v4[j] = (h4 ? v8[j + 4] : v8[j]) +
                    __shfl_xor(h4 ? v8[j] : v8[j + 4], 16, 64);
        const bool h3 = (lane & 8) != 0;
        float v2[2];
        #pragma unroll
        for (int j = 0; j < 2; ++j)
            v2[j] = (h3 ? v4[j + 2] : v4[j]) +
                    __shfl_xor(h3 ? v4[j] : v4[j + 2], 8, 64);
        const bool h2 = (lane & 4) != 0;
        float v1 = (h2 ? v2[1] : v2[0]) +
                   __shfl_xor(h2 ? v2[0] : v2[1], 4, 64);
        v1 += __shfl_xor(v1, 2, 64);
        v1 += __shfl_xor(v1, 1, 64);
        // every lane holds col (lane>>2); pair up cols (2p,2p+1) on lanes 8p
        float vnext = __shfl_down(v1, 4, 64);
        if ((lane & 7) == 0) {
            float di = rsqrtf((float)(deg[r] + 1));
            h1s[(size_t)r * 8 + (lane >> 3)] = packbf(di * v1, di * vnext);
        }
    };

    int r0 = blockIdx.x * 4 + wav;
    int r1 = r0 + stride;
    float4 a0, a1, b0, b1;
    if (r0 < n) {
        a0 = xv[(size_t)r0 * 128 + lane];
        a1 = xv[(size_t)r0 * 128 + 64 + lane];
    }
    if (r1 < n) {
        b0 = xv[(size_t)r1 * 128 + lane];
        b1 = xv[(size_t)r1 * 128 + 64 + lane];
    }

    while (r0 < n) {
        float4 ca0 = a0, ca1 = a1;
        int pr = r0 + 2 * stride;
        if (pr < n) {
            a0 = xv[(size_t)pr * 128 + lane];
            a1 = xv[(size_t)pr * 128 + 64 + lane];
        }
        process(ca0, ca1, r0);
        if (r1 < n) {
            float4 cb0 = b0, cb1 = b1;
            int pr2 = r1 + 2 * stride;
            if (pr2 < n) {
                b0 = xv[(size_t)pr2 * 128 + lane];
                b1 = xv[(size_t)pr2 * 128 + 64 + lane];
            }
            process(cb0, cb1, r1);
        }
        r0 += 2 * stride;
        r1 += 2 * stride;
    }
}

// ---------------- agg1: per-bucket LDS accumulate + self + bias + relu ----------------
// One block per bucket. 2 lanes/edge: lane p loads 16B (features p*8..p*8+7)
// of h1s[src], ds_add_f32 into acc[dlow]. Finish: +self, *dinv, +b1, relu,
// *dinv, pack bf16 -> hs2.

__global__ __launch_bounds__(512) void k_agg1(
    const unsigned int* __restrict__ binned, const int* __restrict__ cnt,
    const int* __restrict__ deg, const uint4* __restrict__ h1s,
    const float* __restrict__ b1, uint4* __restrict__ hs2, int n) {
    __shared__ float acc[BNODES * 17];
    const int b = blockIdx.x;
    const int t = threadIdx.x;
    const int base = b * MAXPB;
    const int ne = cnt[b];
    const int p = t & 1;

    for (int i = t; i < BNODES * 17; i += 512) acc[i] = 0.f;
    __syncthreads();

    for (int i = (t >> 1); i < ne; i += 256) {
        unsigned int v = binned[base + i];
        unsigned int srcI = v & 0xFFFFFu;
        unsigned int dlow = v >> 20;
        uint4 u = h1s[srcI * 2 + p];
        float* a = acc + dlow * 17 + p * 8;
        ldsAdd(a + 0, bflo(u.x)); ldsAdd(a + 1, bfhi(u.x));
        ldsAdd(a + 2, bflo(u.y)); ldsAdd(a + 3, bfhi(u.y));
        ldsAdd(a + 4, bflo(u.z)); ldsAdd(a + 5, bfhi(u.z));
        ldsAdd(a + 6, bflo(u.w)); ldsAdd(a + 7, bfhi(u.w));
    }
    __syncthreads();

    if (t < BNODES) {
        int node = b * BNODES + t;
        if (node < n) {
            float di = rsqrtf((float)(deg[node] + 1));
            uint4 s0 = h1s[node * 2], s1 = h1s[node * 2 + 1];
            float self[16] = {bflo(s0.x), bfhi(s0.x), bflo(s0.y), bfhi(s0.y),
                              bflo(s0.z), bfhi(s0.z), bflo(s0.w), bfhi(s0.w),
                              bflo(s1.x), bfhi(s1.x), bflo(s1.y), bfhi(s1.y),
                              bflo(s1.z), bfhi(s1.z), bflo(s1.w), bfhi(s1.w)};
            const float* a = acc + t * 17;
            float o[16];
            #pragma unroll
            for (int k = 0; k < 16; ++k) {
                float s = a[k] + self[k];
                o[k] = di * fmaxf(fmaf(di, s, b1[k]), 0.f);
            }
            uint4 w0, w1;
            w0.x = packbf(o[0], o[1]);   w0.y = packbf(o[2], o[3]);
            w0.z = packbf(o[4], o[5]);   w0.w = packbf(o[6], o[7]);
            w1.x = packbf(o[8], o[9]);   w1.y = packbf(o[10], o[11]);
            w1.z = packbf(o[12], o[13]); w1.w = packbf(o[14], o[15]);
            hs2[node * 2] = w0;
            hs2[node * 2 + 1] = w1;
        }
    }
}

// ---------------- agg2: per-bucket accumulate + W2 + b2 + log_softmax ----------------

__global__ __launch_bounds__(512) void k_agg2(
    const unsigned int* __restrict__ binned, const int* __restrict__ cnt,
    const int* __restrict__ deg, const uint4* __restrict__ hs2,
    const float* __restrict__ W2, const float* __restrict__ b2,
    float* __restrict__ out, int n) {
    __shared__ float acc[BNODES * 17];
    __shared__ float w2s[NF1 * NF2];
    __shared__ float b2s[NF2];
    const int b = blockIdx.x;
    const int t = threadIdx.x;
    const int base = b * MAXPB;
    const int ne = cnt[b];
    const int p = t & 1;

    for (int i = t; i < NF1 * NF2; i += 512) w2s[i] = W2[i];
    if (t < NF2) b2s[t] = b2[t];
    for (int i = t; i < BNODES * 17; i += 512) acc[i] = 0.f;
    __syncthreads();

    for (int i = (t >> 1); i < ne; i += 256) {
        unsigned int v = binned[base + i];
        unsigned int srcI = v & 0xFFFFFu;
        unsigned int dlow = v >> 20;
        uint4 u = hs2[srcI * 2 + p];
        float* a = acc + dlow * 17 + p * 8;
        ldsAdd(a + 0, bflo(u.x)); ldsAdd(a + 1, bfhi(u.x));
        ldsAdd(a + 2, bflo(u.y)); ldsAdd(a + 3, bfhi(u.y));
        ldsAdd(a + 4, bflo(u.z)); ldsAdd(a + 5, bfhi(u.z));
        ldsAdd(a + 6, bflo(u.w)); ldsAdd(a + 7, bfhi(u.w));
    }
    __syncthreads();

    if (t < BNODES) {
        int node = b * BNODES + t;
        if (node < n) {
            float di = rsqrtf((float)(deg[node] + 1));
            uint4 s0 = hs2[node * 2], s1 = hs2[node * 2 + 1];
            float self[16] = {bflo(s0.x), bfhi(s0.x), bflo(s0.y), bfhi(s0.y),
                              bflo(s0.z), bfhi(s0.z), bflo(s0.w), bfhi(s0.w),
                              bflo(s1.x), bfhi(s1.x), bflo(s1.y), bfhi(s1.y),
                              bflo(s1.z), bfhi(s1.z), bflo(s1.w), bfhi(s1.w)};
            float* a = acc + t * 17;
            #pragma unroll
            for (int k = 0; k < 16; ++k)
                a[k] = di * (a[k] + self[k]);
        }
    }
    __syncthreads();

    const int wav = t >> 6, lane = t & 63;
    const int nbase = b * BNODES + wav * 16;
    #pragma unroll 4
    for (int q = 0; q < 16; ++q) {
        int nd = nbase + q;
        if (nd >= n) break;  // nd uniform across wave
        const float* a = acc + (wav * 16 + q) * 17;
        float av[16];
        #pragma unroll
        for (int k = 0; k < 16; ++k) av[k] = a[k];
        float d = -1e30f;
        if (lane < NF2) {
            d = b2s[lane];
            #pragma unroll
            for (int k = 0; k < 16; ++k) d = fmaf(av[k], w2s[k * NF2 + lane], d);
        }
        float m = d;
        #pragma unroll
        for (int off = 32; off; off >>= 1) m = fmaxf(m, __shfl_xor(m, off, 64));
        float e2 = (lane < NF2) ? __expf(d - m) : 0.f;
        float ssum = e2;
        #pragma unroll
        for (int off = 32; off; off >>= 1) ssum += __shfl_xor(ssum, off, 64);
        float ls = __logf(ssum);
        if (lane < NF2) out[(size_t)nd * NF2 + lane] = d - m - ls;
    }
}

// ---------------- launch ----------------

extern "C" void kernel_launch(void* const* d_in, const int* in_sizes, int n_in,
                              void* d_out, int out_size, void* d_ws, size_t ws_size,
                              hipStream_t stream) {
    const float* x  = (const float*)d_in[0];
    const int*   ei = (const int*)d_in[1];
    const float* W1 = (const float*)d_in[2];
    const float* b1 = (const float*)d_in[3];
    const float* W2 = (const float*)d_in[4];
    const float* b2 = (const float*)d_in[5];
    float* out = (float*)d_out;

    const int N = in_sizes[0] / NF0;  // 100000
    const int E = in_sizes[1] / 2;    // 3200000
    const int NB = (N + BNODES - 1) / BNODES;  // 782
    const int* src = ei;
    const int* dst = ei + E;

    char* ws = (char*)d_ws;
    size_t off = 0;
    auto alloc = [&](size_t bytes) -> void* {
        void* p = ws + off;
        off = (off + bytes + 255) & ~(size_t)255;
        return p;
    };
    int* deg    = (int*)alloc((size_t)(N + NB) * 4);  // deg[N] then cursor[NB]
    int* cursor = deg + N;
    unsigned int* binned = (unsigned int*)alloc((size_t)NB * MAXPB * 4);
    unsigned int* h1s = (unsigned int*)alloc((size_t)N * 8 * 4);
    unsigned int* hs2 = (unsigned int*)alloc((size_t)N * 8 * 4);

    const int nchunks = 1024;                  // 4 blocks/CU exactly
    const int chunkSz = (E + nchunks - 1) / nchunks;  // 3125
    const size_t sortLds = 2 * (size_t)NB * 4;

    k_zero   <<<(N + NB + 255) / 256, 256, 0, stream>>>(deg, N + NB);
    k_binsort<<<nchunks, 256, sortLds, stream>>>(src, dst, cursor, deg, binned,
                                                 E, NB, chunkSz);
    k_gemm1  <<<1024, 256, 0, stream>>>(x, W1, deg, h1s, N);
    k_agg1   <<<NB, 512, 0, stream>>>(binned, cursor, deg, (const uint4*)h1s,
                                      b1, (uint4*)hs2, N);
    k_agg2   <<<NB, 512, 0, stream>>>(binned, cursor, deg, (const uint4*)hs2,
                                      W2, b2, out, N);
}

// Round 5
// 497.069 us; speedup vs baseline: 2.3695x; 2.3695x over previous
//
#include <hip/hip_runtime.h>
#include <hip/hip_bf16.h>

// GCN 2-layer: N=100000, E=3200000, F 512->16->40, fp32 in/out.
// Pipeline (6 dispatches): zero(cursor) -> binsort (LDS counting-sort into
// slotted buckets) -> build (LDS-staged per-bucket CSR + oe + dinv) ->
// GEMM1 (W-in-regs, shuffle butterfly, bf16 out) -> gather1 (wave-per-node,
// coalesced csr, +relu+bias, bf16) -> g2f (wave-per-node gather + W2 + b2 +
// log_softmax).
// bf16 tables (3.2MB) stay L2-resident. NO per-edge global atomics, NO float
// LDS atomics (both measured catastrophic in round 4).

#define NF0 512
#define NF1 16
#define NF2 40
#define BSHIFT 7            // 128 nodes per bucket
#define BNODES 128
#define CHUNK 4096          // edges per binsort block (33KB LDS -> 4 blk/CU)
#define MAXPB 5120          // slots per bucket; mean 4096, sigma 64 -> +16 sigma

// bf16 pair helpers: uint u = bf16(lo) | bf16(hi)<<16
__device__ __forceinline__ float bflo(unsigned int u) { return __uint_as_float(u << 16); }
__device__ __forceinline__ float bfhi(unsigned int u) { return __uint_as_float(u & 0xFFFF0000u); }
__device__ __forceinline__ unsigned int packbf(float lo, float hi) {
    unsigned int bl = __float_as_uint(lo);
    bl = (bl + 0x7FFFu + ((bl >> 16) & 1u)) >> 16;
    unsigned int bh = __float_as_uint(hi);
    bh = (bh + 0x7FFFu + ((bh >> 16) & 1u)) & 0xFFFF0000u;
    return bl | bh;
}

#define ACC8(A, u)                                         \
    do {                                                   \
        A[0] += bflo((u).x); A[1] += bfhi((u).x);          \
        A[2] += bflo((u).y); A[3] += bfhi((u).y);          \
        A[4] += bflo((u).z); A[5] += bfhi((u).z);          \
        A[6] += bflo((u).w); A[7] += bfhi((u).w);          \
    } while (0)

// ---------------- zero bucket cursors ----------------

__global__ void k_zero(int* __restrict__ p, int n) {
    int i = blockIdx.x * 256 + threadIdx.x;
    if (i < n) p[i] = 0;
}

// ---------------- binning: counting sort CHUNK edges by bucket in LDS ----------------
// Writes into slotted layout binned[b*MAXPB + slot]; cursor[b] ends as count.

__global__ __launch_bounds__(256) void k_binsort(
    const int* __restrict__ src, const int* __restrict__ dst,
    int* __restrict__ cursor, unsigned int* __restrict__ binned, int E, int NB) {
    __shared__ unsigned int sorted[CHUNK];
    __shared__ unsigned short bid[CHUNK];
    extern __shared__ int dyn[];
    int* hist = dyn;            // NB (reused as local cursor)
    int* lstart = dyn + NB;     // NB
    int* gbase = dyn + 2 * NB;  // NB
    __shared__ int wtot[4];

    const int t = threadIdx.x;
    const int lane = t & 63, wav = t >> 6;
    const int base = blockIdx.x * CHUNK;
    const int ne = min(CHUNK, E - base);

    for (int i = t; i < NB; i += 256) hist[i] = 0;
    __syncthreads();

    for (int i = t; i < ne; i += 256) atomicAdd(&hist[dst[base + i] >> BSHIFT], 1);
    __syncthreads();

    {
        int eb = t * 4;
        int loc[4];
        int tsum = 0;
        #pragma unroll
        for (int q = 0; q < 4; ++q) {
            loc[q] = (eb + q < NB) ? hist[eb + q] : 0;
            tsum += loc[q];
        }
        int v = tsum;
        #pragma unroll
        for (int off = 1; off < 64; off <<= 1) {
            int y = __shfl_up(v, off, 64);
            if (lane >= off) v += y;
        }
        if (lane == 63) wtot[wav] = v;
        __syncthreads();
        int wbase = 0;
        #pragma unroll
        for (int w = 0; w < 4; ++w) wbase += (w < wav) ? wtot[w] : 0;
        int run = wbase + v - tsum;
        #pragma unroll
        for (int q = 0; q < 4; ++q) {
            if (eb + q < NB) lstart[eb + q] = run;
            run += loc[q];
        }
    }
    __syncthreads();

    for (int b = t; b < NB; b += 256) {
        int c = hist[b];
        if (c > 0) gbase[b] = b * MAXPB + atomicAdd(&cursor[b], c);
        hist[b] = lstart[b];
    }
    __syncthreads();

    for (int i = t; i < ne; i += 256) {
        int d = dst[base + i];
        int s = src[base + i];
        int b = d >> BSHIFT;
        int pos = atomicAdd(&hist[b], 1);
        sorted[pos] = ((unsigned int)(d & (BNODES - 1)) << 20) | (unsigned int)s;
        bid[pos] = (unsigned short)b;
    }
    __syncthreads();

    for (int i = t; i < ne; i += 256) {
        int b = bid[i];
        binned[gbase[b] + (i - lstart[b])] = sorted[i];
    }
}

// ---------------- per-bucket CSR build (LDS-staged, single global read) ----------------

__global__ __launch_bounds__(256) void k_build(
    const unsigned int* __restrict__ binned, const int* __restrict__ cnt_in,
    int* __restrict__ csr, int2* __restrict__ oe,
    float* __restrict__ dinv, int n) {
    __shared__ unsigned int ebuf[MAXPB];   // 20KB staged bucket edges
    __shared__ int cnt[BNODES];
    __shared__ int lcur[BNODES];
    __shared__ int excl[BNODES];
    const int b = blockIdx.x;
    const int t = threadIdx.x;
    const int lane = t & 63, wav = t >> 6;
    const int s0 = b * MAXPB;
    const int ne = cnt_in[b];

    if (t < BNODES) cnt[t] = 0;
    __syncthreads();
    for (int i = t; i < ne; i += 256) {
        unsigned int v = binned[s0 + i];
        ebuf[i] = v;
        atomicAdd(&cnt[v >> 20], 1);
    }
    __syncthreads();

    if (wav == 0) {
        int c0 = cnt[2 * lane], c1 = cnt[2 * lane + 1];
        int v = c0 + c1;
        #pragma unroll
        for (int off = 1; off < 64; off <<= 1) {
            int y = __shfl_up(v, off, 64);
            if (lane >= off) v += y;
        }
        int ex = v - c0 - c1;
        excl[2 * lane] = ex;
        excl[2 * lane + 1] = ex + c0;
        lcur[2 * lane] = ex;
        lcur[2 * lane + 1] = ex + c0;
    }
    __syncthreads();

    if (t < BNODES) {
        int node = b * BNODES + t;
        if (node < n) {
            int deg = cnt[t] + 1;  // + self loop
            dinv[node] = rsqrtf((float)deg);
            int o = s0 + excl[t];
            oe[node] = make_int2(o, o + cnt[t]);
        }
    }
    __syncthreads();

    for (int i = t; i < ne; i += 256) {
        unsigned int v = ebuf[i];
        int dlow = v >> 20;
        int pos = atomicAdd(&lcur[dlow], 1);
        csr[s0 + pos] = (int)(v & 0xFFFFFu);
    }
}

// ---------------- GEMM1: h1s[n][c] = bf16( dinv[n] * sum_k x[n][k]*W1[k][c] ) ----------
// One wave per row, barrier-free; W1 in 128 VGPRs; shuffle-butterfly reduce;
// 2-deep row prefetch. Output packed bf16 pairs (8 uints/row).

__global__ __launch_bounds__(256, 2) void k_gemm1(
    const float* __restrict__ x, const float* __restrict__ W1,
    const float* __restrict__ dinv, unsigned int* __restrict__ h1s, int n) {
    const int lane = threadIdx.x & 63;
    const int wav = threadIdx.x >> 6;

    float wA[4][16], wB[4][16];
    const float4* W1v = (const float4*)W1;
    #pragma unroll
    for (int j = 0; j < 4; ++j) {
        #pragma unroll
        for (int q = 0; q < 4; ++q) {
            float4 wa = W1v[(4 * lane + j) * 4 + q];
            wA[j][4 * q + 0] = wa.x; wA[j][4 * q + 1] = wa.y;
            wA[j][4 * q + 2] = wa.z; wA[j][4 * q + 3] = wa.w;
            float4 wb = W1v[(256 + 4 * lane + j) * 4 + q];
            wB[j][4 * q + 0] = wb.x; wB[j][4 * q + 1] = wb.y;
            wB[j][4 * q + 2] = wb.z; wB[j][4 * q + 3] = wb.w;
        }
    }

    const float4* xv = (const float4*)x;
    const int stride = gridDim.x * 4;

    auto process = [&](float4 p0, float4 p1, int r) {
        float part[16];
        #pragma unroll
        for (int c = 0; c < 16; ++c) part[c] = 0.f;
        float av[8] = {p0.x, p0.y, p0.z, p0.w, p1.x, p1.y, p1.z, p1.w};
        #pragma unroll
        for (int j = 0; j < 4; ++j) {
            #pragma unroll
            for (int c = 0; c < 16; ++c) {
                part[c] = fmaf(av[j], wA[j][c], part[c]);
                part[c] = fmaf(av[4 + j], wB[j][c], part[c]);
            }
        }
        const bool h5 = (lane & 32) != 0;
        float v8[8];
        #pragma unroll
        for (int j = 0; j < 8; ++j)
            v8[j] = (h5 ? part[j + 8] : part[j]) +
                    __shfl_xor(h5 ? part[j] : part[j + 8], 32, 64);
        const bool h4 = (lane & 16) != 0;
        float v4[4];
        #pragma unroll
        for (int j = 0; j < 4; ++j)
            v4[j] = (h4 ? v8[j + 4] : v8[j]) +
                    __shfl_xor(h4 ? v8[j] : v8[j + 4], 16, 64);
        const bool h3 = (lane & 8) != 0;
        float v2[2];
        #pragma unroll
        for (int j = 0; j < 2; ++j)
            v2[j] = (h3 ? v4[j + 2] : v4[j]) +
                    __shfl_xor(h3 ? v4[j] : v4[j + 2], 8, 64);
        const bool h2 = (lane & 4) != 0;
        float v1 = (h2 ? v2[1] : v2[0]) +
                   __shfl_xor(h2 ? v2[0] : v2[1], 4, 64);
        v1 += __shfl_xor(v1, 2, 64);
        v1 += __shfl_xor(v1, 1, 64);
        // every lane holds col (lane>>2); pair up cols (2p,2p+1) on lanes 8p
        float vnext = __shfl_down(v1, 4, 64);
        if ((lane & 7) == 0) {
            float di = dinv[r];
            h1s[(size_t)r * 8 + (lane >> 3)] = packbf(di * v1, di * vnext);
        }
    };

    int r0 = blockIdx.x * 4 + wav;
    int r1 = r0 + stride;
    float4 a0, a1, b0, b1;
    if (r0 < n) {
        a0 = xv[(size_t)r0 * 128 + lane];
        a1 = xv[(size_t)r0 * 128 + 64 + lane];
    }
    if (r1 < n) {
        b0 = xv[(size_t)r1 * 128 + lane];
        b1 = xv[(size_t)r1 * 128 + 64 + lane];
    }

    while (r0 < n) {
        float4 ca0 = a0, ca1 = a1;
        int pr = r0 + 2 * stride;
        if (pr < n) {
            a0 = xv[(size_t)pr * 128 + lane];
            a1 = xv[(size_t)pr * 128 + 64 + lane];
        }
        process(ca0, ca1, r0);
        if (r1 < n) {
            float4 cb0 = b0, cb1 = b1;
            int pr2 = r1 + 2 * stride;
            if (pr2 < n) {
                b0 = xv[(size_t)pr2 * 128 + lane];
                b1 = xv[(size_t)pr2 * 128 + 64 + lane];
            }
            process(cb0, cb1, r1);
        }
        r0 += 2 * stride;
        r1 += 2 * stride;
    }
}

// ---------------- gather1: wave-per-node, 32 edges x 2 halves per round ----------------
// lane l: edge k=l>>1, half p=l&1. csr reads coalesced (2-way broadcast free).
// Reduce via shfl_xor 2..32 (even offsets preserve p-partition).

__global__ __launch_bounds__(256) void k_gather1(
    const int2* __restrict__ oe, const int* __restrict__ csr,
    const uint4* __restrict__ h1s, const float* __restrict__ dinv,
    const float* __restrict__ b1, uint4* __restrict__ hs2, int n) {
    int gw = (blockIdx.x * 256 + threadIdx.x) >> 6;  // global wave = node
    if (gw >= n) return;
    const int l = threadIdx.x & 63, p = l & 1, k = l >> 1;
    int2 r = oe[gw];
    const int off = r.x, deg = r.y - r.x;

    float A[8];
    #pragma unroll
    for (int q = 0; q < 8; ++q) A[q] = 0.f;
    for (int base = 0; base < deg; base += 32) {
        int kk = base + k;
        if (kk < deg) {
            int s = csr[off + kk];
            uint4 u = h1s[(unsigned)s * 2 + p];
            ACC8(A, u);
        }
    }
    #pragma unroll
    for (int q = 0; q < 8; ++q) {
        A[q] += __shfl_xor(A[q], 2, 64);
        A[q] += __shfl_xor(A[q], 4, 64);
        A[q] += __shfl_xor(A[q], 8, 64);
        A[q] += __shfl_xor(A[q], 16, 64);
        A[q] += __shfl_xor(A[q], 32, 64);
    }
    if (k == 0) {  // lanes 0,1: self loop + epilogue + write
        uint4 su = h1s[(unsigned)gw * 2 + p];
        ACC8(A, su);
        float di = dinv[gw];
        const float4* b1v = (const float4*)b1;
        float4 q0 = b1v[2 * p], q1 = b1v[2 * p + 1];
        float bias[8] = {q0.x, q0.y, q0.z, q0.w, q1.x, q1.y, q1.z, q1.w};
        float o[8];
        #pragma unroll
        for (int q = 0; q < 8; ++q)
            o[q] = di * fmaxf(fmaf(di, A[q], bias[q]), 0.f);
        uint4 w;
        w.x = packbf(o[0], o[1]); w.y = packbf(o[2], o[3]);
        w.z = packbf(o[4], o[5]); w.w = packbf(o[6], o[7]);
        hs2[(unsigned)gw * 2 + p] = w;
    }
}

// ---------------- g2f: wave-per-node gather + W2 + b2 + log_softmax ----------------

__global__ __launch_bounds__(256) void k_g2f(
    const int2* __restrict__ oe, const int* __restrict__ csr,
    const uint4* __restrict__ hs2, const float* __restrict__ dinv,
    const float* __restrict__ W2, const float* __restrict__ b2,
    float* __restrict__ out, int n) {
    __shared__ float w2s[NF1 * NF2];
    __shared__ float b2s[NF2];
    __shared__ float agg[4][17];
    for (int i = threadIdx.x; i < NF1 * NF2; i += 256) w2s[i] = W2[i];
    if (threadIdx.x < NF2) b2s[threadIdx.x] = b2[threadIdx.x];

    const int wav = threadIdx.x >> 6, lane = threadIdx.x & 63;
    int gw = blockIdx.x * 4 + wav;  // node
    const int p = lane & 1, k = lane >> 1;

    if (gw < n) {
        int2 r = oe[gw];
        const int off = r.x, deg = r.y - r.x;
        float A[8];
        #pragma unroll
        for (int q = 0; q < 8; ++q) A[q] = 0.f;
        for (int base = 0; base < deg; base += 32) {
            int kk = base + k;
            if (kk < deg) {
                int s = csr[off + kk];
                uint4 u = hs2[(unsigned)s * 2 + p];
                ACC8(A, u);
            }
        }
        #pragma unroll
        for (int q = 0; q < 8; ++q) {
            A[q] += __shfl_xor(A[q], 2, 64);
            A[q] += __shfl_xor(A[q], 4, 64);
            A[q] += __shfl_xor(A[q], 8, 64);
            A[q] += __shfl_xor(A[q], 16, 64);
            A[q] += __shfl_xor(A[q], 32, 64);
        }
        if (k == 0) {
            uint4 su = hs2[(unsigned)gw * 2 + p];
            ACC8(A, su);
            float di = dinv[gw];
            #pragma unroll
            for (int q = 0; q < 8; ++q) agg[wav][8 * p + q] = di * A[q];
        }
    }
    __syncthreads();

    if (gw >= n) return;
    float av[16];
    #pragma unroll
    for (int q = 0; q < 16; ++q) av[q] = agg[wav][q];
    float d = -1e30f;
    if (lane < NF2) {
        d = b2s[lane];
        #pragma unroll
        for (int q = 0; q < 16; ++q) d = fmaf(av[q], w2s[q * NF2 + lane], d);
    }
    float m = d;
    #pragma unroll
    for (int off2 = 32; off2; off2 >>= 1) m = fmaxf(m, __shfl_xor(m, off2, 64));
    float e2 = (lane < NF2) ? __expf(d - m) : 0.f;
    float ssum = e2;
    #pragma unroll
    for (int off2 = 32; off2; off2 >>= 1) ssum += __shfl_xor(ssum, off2, 64);
    float ls = __logf(ssum);
    if (lane < NF2) out[(size_t)gw * NF2 + lane] = d - m - ls;
}

// ---------------- launch ----------------

extern "C" void kernel_launch(void* const* d_in, const int* in_sizes, int n_in,
                              void* d_out, int out_size, void* d_ws, size_t ws_size,
                              hipStream_t stream) {
    const float* x  = (const float*)d_in[0];
    const int*   ei = (const int*)d_in[1];
    const float* W1 = (const float*)d_in[2];
    const float* b1 = (const float*)d_in[3];
    const float* W2 = (const float*)d_in[4];
    const float* b2 = (const float*)d_in[5];
    float* out = (float*)d_out;

    const int N = in_sizes[0] / NF0;  // 100000
    const int E = in_sizes[1] / 2;    // 3200000
    const int NB = (N + BNODES - 1) / BNODES;  // 782
    const int* src = ei;
    const int* dst = ei + E;

    char* ws = (char*)d_ws;
    size_t off = 0;
    auto alloc = [&](size_t bytes) -> void* {
        void* p = ws + off;
        off = (off + bytes + 255) & ~(size_t)255;
        return p;
    };
    int*   cursor = (int*)alloc((size_t)NB * 4);
    unsigned int* binned = (unsigned int*)alloc((size_t)NB * MAXPB * 4);
    int*   csr    = (int*)alloc((size_t)NB * MAXPB * 4);
    int2*  oe     = (int2*)alloc((size_t)N * 8);
    float* dinv   = (float*)alloc((size_t)N * 4);
    // binned dead after k_build: reuse for bf16 h1s/hs2 (3.2MB each)
    unsigned int* h1s = binned;
    unsigned int* hs2 = binned + (size_t)N * 8;

    const int eb = (E + CHUNK - 1) / CHUNK;  // 782
    const size_t histBytes = (size_t)NB * 4;
    const int wblocks = (N + 3) / 4;          // wave-per-node: 4 nodes/block

    k_zero   <<<(NB + 255) / 256, 256, 0, stream>>>(cursor, NB);
    k_binsort<<<eb, 256, 3 * histBytes, stream>>>(src, dst, cursor, binned, E, NB);
    k_build  <<<NB, 256, 0, stream>>>(binned, cursor, csr, oe, dinv, N);
    k_gemm1  <<<1024, 256, 0, stream>>>(x, W1, dinv, h1s, N);
    k_gather1<<<wblocks, 256, 0, stream>>>(oe, csr, (const uint4*)h1s, dinv, b1,
                                           (uint4*)hs2, N);
    k_g2f    <<<wblocks, 256, 0, stream>>>(oe, csr, (const uint4*)hs2, dinv, W2, b2,
                                           out, N);
}

// Round 6
// 431.678 us; speedup vs baseline: 2.7285x; 1.1515x over previous
//
#include <hip/hip_runtime.h>
#include <hip/hip_bf16.h>

// GCN 2-layer: N=100000, E=3200000, F 512->16->40, fp32 in/out.
// Pipeline (5 dispatches):
//   zero(cursor) ->
//   FUSED sortgemm: blocks [0,SORTB) = LDS counting-sort binning into slotted
//     buckets; blocks [SORTB,SORTB+1024) = GEMM1 (W-in-regs, shuffle
//     butterfly) writing UNSCALED fp32 h1f. HBM-bound GEMM overlaps
//     LDS-bound sort on the same CUs. ->
//   build: LDS-staged per-bucket CSR + oe + dinv + tail that writes
//     h1s = bf16(dinv * h1f) (single rounding, same numerics as before) ->
//   gather1 (8 lanes/node = 4 segs x 2 halves, uint4, +bias+relu, bf16) ->
//   g2f (same gather + W2 + b2 + log_softmax).
// bf16 tables (3.2MB) stay L2-resident. NO per-edge global atomics, NO float
// LDS atomics (both measured catastrophic in round 4). Wave-per-node gathers
// measured -55us worse (round 5) -> seg-split form kept.

#define NF0 512
#define NF1 16
#define NF2 40
#define BSHIFT 7            // 128 nodes per bucket
#define BNODES 128
#define CHUNK 8192          // edges per binsort block
#define MAXPB 5120          // slots per bucket; mean 4096, sigma 64 -> +16 sigma
#define NBMAX 800           // >= NB = 782

// bf16 pair helpers: uint u = bf16(lo) | bf16(hi)<<16
__device__ __forceinline__ float bflo(unsigned int u) { return __uint_as_float(u << 16); }
__device__ __forceinline__ float bfhi(unsigned int u) { return __uint_as_float(u & 0xFFFF0000u); }
__device__ __forceinline__ unsigned int packbf(float lo, float hi) {
    unsigned int bl = __float_as_uint(lo);
    bl = (bl + 0x7FFFu + ((bl >> 16) & 1u)) >> 16;
    unsigned int bh = __float_as_uint(hi);
    bh = (bh + 0x7FFFu + ((bh >> 16) & 1u)) & 0xFFFF0000u;
    return bl | bh;
}

#define ACC8(A, u)                                         \
    do {                                                   \
        A[0] += bflo((u).x); A[1] += bfhi((u).x);          \
        A[2] += bflo((u).y); A[3] += bfhi((u).y);          \
        A[4] += bflo((u).z); A[5] += bfhi((u).z);          \
        A[6] += bflo((u).w); A[7] += bfhi((u).w);          \
    } while (0)

// ---------------- zero bucket cursors ----------------

__global__ void k_zero(int* __restrict__ p, int n) {
    int i = blockIdx.x * 256 + threadIdx.x;
    if (i < n) p[i] = 0;
}

// ---------------- FUSED: binsort (blocks < SORTB) + GEMM1 (rest) ----------------

__global__ __launch_bounds__(256, 2) void k_sortgemm(
    const int* __restrict__ src, const int* __restrict__ dst,
    int* __restrict__ cursor, unsigned int* __restrict__ binned,
    const float* __restrict__ x, const float* __restrict__ W1,
    float* __restrict__ h1f, int E, int NB, int SORTB, int n) {
    if (blockIdx.x < SORTB) {
        // ---------- binsort path (round-3 proven body, static LDS) ----------
        __shared__ unsigned int sorted[CHUNK];
        __shared__ unsigned short bid[CHUNK];
        __shared__ int hist[NBMAX];
        __shared__ int lstart[NBMAX];
        __shared__ int gbase[NBMAX];
        __shared__ int wtot[4];

        const int t = threadIdx.x;
        const int lane = t & 63, wav = t >> 6;
        const int base = blockIdx.x * CHUNK;
        const int ne = min(CHUNK, E - base);

        for (int i = t; i < NB; i += 256) hist[i] = 0;
        __syncthreads();

        for (int i = t; i < ne; i += 256)
            atomicAdd(&hist[dst[base + i] >> BSHIFT], 1);
        __syncthreads();

        {
            int eb = t * 4;
            int loc[4];
            int tsum = 0;
            #pragma unroll
            for (int q = 0; q < 4; ++q) {
                loc[q] = (eb + q < NB) ? hist[eb + q] : 0;
                tsum += loc[q];
            }
            int v = tsum;
            #pragma unroll
            for (int off = 1; off < 64; off <<= 1) {
                int y = __shfl_up(v, off, 64);
                if (lane >= off) v += y;
            }
            if (lane == 63) wtot[wav] = v;
            __syncthreads();
            int wbase = 0;
            #pragma unroll
            for (int w = 0; w < 4; ++w) wbase += (w < wav) ? wtot[w] : 0;
            int run = wbase + v - tsum;
            #pragma unroll
            for (int q = 0; q < 4; ++q) {
                if (eb + q < NB) lstart[eb + q] = run;
                run += loc[q];
            }
        }
        __syncthreads();

        for (int b = t; b < NB; b += 256) {
            int c = hist[b];
            if (c > 0) gbase[b] = b * MAXPB + atomicAdd(&cursor[b], c);
            hist[b] = lstart[b];
        }
        __syncthreads();

        for (int i = t; i < ne; i += 256) {
            int d = dst[base + i];
            int s = src[base + i];
            int b = d >> BSHIFT;
            int pos = atomicAdd(&hist[b], 1);
            sorted[pos] = ((unsigned int)(d & (BNODES - 1)) << 20) | (unsigned int)s;
            bid[pos] = (unsigned short)b;
        }
        __syncthreads();

        for (int i = t; i < ne; i += 256) {
            int b = bid[i];
            binned[gbase[b] + (i - lstart[b])] = sorted[i];
        }
    } else {
        // ---------- GEMM1 path: unscaled fp32 out ----------
        const int lane = threadIdx.x & 63;
        const int wav = threadIdx.x >> 6;
        const int gb = blockIdx.x - SORTB;
        const int NGEMM = gridDim.x - SORTB;

        float wA[4][16], wB[4][16];
        const float4* W1v = (const float4*)W1;
        #pragma unroll
        for (int j = 0; j < 4; ++j) {
            #pragma unroll
            for (int q = 0; q < 4; ++q) {
                float4 wa = W1v[(4 * lane + j) * 4 + q];
                wA[j][4 * q + 0] = wa.x; wA[j][4 * q + 1] = wa.y;
                wA[j][4 * q + 2] = wa.z; wA[j][4 * q + 3] = wa.w;
                float4 wb = W1v[(256 + 4 * lane + j) * 4 + q];
                wB[j][4 * q + 0] = wb.x; wB[j][4 * q + 1] = wb.y;
                wB[j][4 * q + 2] = wb.z; wB[j][4 * q + 3] = wb.w;
            }
        }

        const float4* xv = (const float4*)x;
        const int stride = NGEMM * 4;

        auto process = [&](float4 p0, float4 p1, int r) {
            float part[16];
            #pragma unroll
            for (int c = 0; c < 16; ++c) part[c] = 0.f;
            float av[8] = {p0.x, p0.y, p0.z, p0.w, p1.x, p1.y, p1.z, p1.w};
            #pragma unroll
            for (int j = 0; j < 4; ++j) {
                #pragma unroll
                for (int c = 0; c < 16; ++c) {
                    part[c] = fmaf(av[j], wA[j][c], part[c]);
                    part[c] = fmaf(av[4 + j], wB[j][c], part[c]);
                }
            }
            const bool h5 = (lane & 32) != 0;
            float v8[8];
            #pragma unroll
            for (int j = 0; j < 8; ++j)
                v8[j] = (h5 ? part[j + 8] : part[j]) +
                        __shfl_xor(h5 ? part[j] : part[j + 8], 32, 64);
            const bool h4 = (lane & 16) != 0;
            float v4[4];
            #pragma unroll
            for (int j = 0; j < 4; ++j)
                v4[j] = (h4 ? v8[j + 4] : v8[j]) +
                        __shfl_xor(h4 ? v8[j] : v8[j + 4], 16, 64);
            const bool h3 = (lane & 8) != 0;
            float v2[2];
            #pragma unroll
            for (int j = 0; j < 2; ++j)
                v2[j] = (h3 ? v4[j + 2] : v4[j]) +
                        __shfl_xor(h3 ? v4[j] : v4[j + 2], 8, 64);
            const bool h2 = (lane & 4) != 0;
            float v1 = (h2 ? v2[1] : v2[0]) +
                       __shfl_xor(h2 ? v2[0] : v2[1], 4, 64);
            v1 += __shfl_xor(v1, 2, 64);
            v1 += __shfl_xor(v1, 1, 64);
            // lane 4c holds col c; lanes (lane&3)==0 write fp32 (64B/row)
            if ((lane & 3) == 0)
                h1f[(size_t)r * 16 + (lane >> 2)] = v1;
        };

        int r0 = gb * 4 + wav;
        int r1 = r0 + stride;
        float4 a0, a1, b0, b1;
        if (r0 < n) {
            a0 = xv[(size_t)r0 * 128 + lane];
            a1 = xv[(size_t)r0 * 128 + 64 + lane];
        }
        if (r1 < n) {
            b0 = xv[(size_t)r1 * 128 + lane];
            b1 = xv[(size_t)r1 * 128 + 64 + lane];
        }

        while (r0 < n) {
            float4 ca0 = a0, ca1 = a1;
            int pr = r0 + 2 * stride;
            if (pr < n) {
                a0 = xv[(size_t)pr * 128 + lane];
                a1 = xv[(size_t)pr * 128 + 64 + lane];
            }
            process(ca0, ca1, r0);
            if (r1 < n) {
                float4 cb0 = b0, cb1 = b1;
                int pr2 = r1 + 2 * stride;
                if (pr2 < n) {
                    b0 = xv[(size_t)pr2 * 128 + lane];
                    b1 = xv[(size_t)pr2 * 128 + 64 + lane];
                }
                process(cb0, cb1, r1);
            }
            r0 += 2 * stride;
            r1 += 2 * stride;
        }
    }
}

// ---------------- per-bucket CSR build (LDS-staged) + h1 scale tail ----------------

__global__ __launch_bounds__(256) void k_build(
    const unsigned int* __restrict__ binned, const int* __restrict__ cnt_in,
    int* __restrict__ csr, int2* __restrict__ oe, float* __restrict__ dinv,
    const float* __restrict__ h1f, uint4* __restrict__ h1s, int n) {
    __shared__ unsigned int ebuf[MAXPB];   // 20KB staged bucket edges
    __shared__ int cnt[BNODES];
    __shared__ int lcur[BNODES];
    __shared__ int excl[BNODES];
    const int b = blockIdx.x;
    const int t = threadIdx.x;
    const int lane = t & 63, wav = t >> 6;
    const int s0 = b * MAXPB;
    const int ne = cnt_in[b];

    if (t < BNODES) cnt[t] = 0;
    __syncthreads();
    for (int i = t; i < ne; i += 256) {
        unsigned int v = binned[s0 + i];
        ebuf[i] = v;
        atomicAdd(&cnt[v >> 20], 1);
    }
    __syncthreads();

    if (wav == 0) {
        int c0 = cnt[2 * lane], c1 = cnt[2 * lane + 1];
        int v = c0 + c1;
        #pragma unroll
        for (int off = 1; off < 64; off <<= 1) {
            int y = __shfl_up(v, off, 64);
            if (lane >= off) v += y;
        }
        int ex = v - c0 - c1;
        excl[2 * lane] = ex;
        excl[2 * lane + 1] = ex + c0;
        lcur[2 * lane] = ex;
        lcur[2 * lane + 1] = ex + c0;
    }
    __syncthreads();

    if (t < BNODES) {
        int node = b * BNODES + t;
        if (node < n) {
            int deg = cnt[t] + 1;  // + self loop
            float di = rsqrtf((float)deg);
            dinv[node] = di;
            int o = s0 + excl[t];
            oe[node] = make_int2(o, o + cnt[t]);
            // scale tail: h1s[node] = bf16(di * h1f[node]) (single rounding)
            const float4* hf = (const float4*)(h1f + (size_t)node * 16);
            float4 f0 = hf[0], f1 = hf[1], f2 = hf[2], f3 = hf[3];
            uint4 w0, w1;
            w0.x = packbf(di * f0.x, di * f0.y);
            w0.y = packbf(di * f0.z, di * f0.w);
            w0.z = packbf(di * f1.x, di * f1.y);
            w0.w = packbf(di * f1.z, di * f1.w);
            w1.x = packbf(di * f2.x, di * f2.y);
            w1.y = packbf(di * f2.z, di * f2.w);
            w1.z = packbf(di * f3.x, di * f3.y);
            w1.w = packbf(di * f3.z, di * f3.w);
            h1s[(size_t)node * 2] = w0;
            h1s[(size_t)node * 2 + 1] = w1;
        }
    }
    __syncthreads();

    for (int i = t; i < ne; i += 256) {
        unsigned int v = ebuf[i];
        int dlow = v >> 20;
        int pos = atomicAdd(&lcur[dlow], 1);
        csr[s0 + pos] = (int)(v & 0xFFFFFu);
    }
}

// ---------------- gather1: 8 lanes/node = 4 segs x 2 halves, uint4, 4-deep ILP ----------

__global__ __launch_bounds__(256) void k_gather1(
    const int2* __restrict__ oe, const int* __restrict__ csr,
    const uint4* __restrict__ h1s, const float* __restrict__ dinv,
    const float* __restrict__ b1, uint4* __restrict__ hs2, int n) {
    int t = blockIdx.x * 256 + threadIdx.x;
    int node = t >> 3;
    if (node >= n) return;
    const int sub = t & 7, seg = sub >> 1, p = sub & 1;
    int2 r = oe[node];
    const int d = r.y - r.x;
    int j = r.x + ((d * seg) >> 2);
    const int e = r.x + ((d * (seg + 1)) >> 2);
    const char* tab = (const char*)h1s;
    const unsigned pof = (unsigned)(p << 4);

    float A[8], B[8];
    #pragma unroll
    for (int k = 0; k < 8; ++k) { A[k] = 0.f; B[k] = 0.f; }
    if (seg == 0) {  // self loop
        uint4 su = *(const uint4*)(tab + (((unsigned)node << 5) | pof));
        ACC8(A, su);
    }
    for (; j + 3 < e; j += 4) {
        int i0 = csr[j], i1 = csr[j + 1], i2 = csr[j + 2], i3 = csr[j + 3];
        uint4 u0 = *(const uint4*)(tab + (((unsigned)i0 << 5) | pof));
        uint4 u1 = *(const uint4*)(tab + (((unsigned)i1 << 5) | pof));
        uint4 u2 = *(const uint4*)(tab + (((unsigned)i2 << 5) | pof));
        uint4 u3 = *(const uint4*)(tab + (((unsigned)i3 << 5) | pof));
        ACC8(A, u0); ACC8(B, u1); ACC8(A, u2); ACC8(B, u3);
    }
    for (; j < e; ++j) {
        uint4 u = *(const uint4*)(tab + (((unsigned)csr[j] << 5) | pof));
        ACC8(A, u);
    }
    float v[8];
    #pragma unroll
    for (int k = 0; k < 8; ++k) v[k] = A[k] + B[k];
    #pragma unroll
    for (int k = 0; k < 8; ++k) {
        v[k] += __shfl_xor(v[k], 2, 64);
        v[k] += __shfl_xor(v[k], 4, 64);
    }
    if (seg == 0) {
        float di = dinv[node];
        const float4* b1v = (const float4*)b1;
        float4 q0 = b1v[2 * p], q1 = b1v[2 * p + 1];
        float bias[8] = {q0.x, q0.y, q0.z, q0.w, q1.x, q1.y, q1.z, q1.w};
        float o[8];
        #pragma unroll
        for (int k = 0; k < 8; ++k)
            o[k] = di * fmaxf(fmaf(di, v[k], bias[k]), 0.f);
        uint4 w;
        w.x = packbf(o[0], o[1]); w.y = packbf(o[2], o[3]);
        w.z = packbf(o[4], o[5]); w.w = packbf(o[6], o[7]);
        *(uint4*)((char*)hs2 + (((unsigned)node << 5) | pof)) = w;
    }
}

// ---------------- fused gather2 + W2 + b2 + log_softmax ----------------
// Phase 1: same 8-lanes/node seg-split gather. Phase 2: 8 nodes/wave MLP+softmax.

__global__ __launch_bounds__(256) void k_g2f(
    const int2* __restrict__ oe, const int* __restrict__ csr,
    const uint4* __restrict__ hs2, const float* __restrict__ dinv,
    const float* __restrict__ W2, const float* __restrict__ b2,
    float* __restrict__ out, int n) {
    __shared__ float w2s[NF1 * NF2];
    __shared__ float b2s[NF2];
    __shared__ float agg[32][17];
    for (int i = threadIdx.x; i < NF1 * NF2; i += 256) w2s[i] = W2[i];
    if (threadIdx.x < NF2) b2s[threadIdx.x] = b2[threadIdx.x];

    int t = blockIdx.x * 256 + threadIdx.x;
    int node = t >> 3;
    const int sub = t & 7, seg = sub >> 1, p = sub & 1;
    const int g = threadIdx.x >> 3;

    if (node < n) {
        int2 r = oe[node];
        const int d = r.y - r.x;
        int j = r.x + ((d * seg) >> 2);
        const int e = r.x + ((d * (seg + 1)) >> 2);
        const char* tab = (const char*)hs2;
        const unsigned pof = (unsigned)(p << 4);

        float A[8], B[8];
        #pragma unroll
        for (int k = 0; k < 8; ++k) { A[k] = 0.f; B[k] = 0.f; }
        if (seg == 0) {  // self loop
            uint4 su = *(const uint4*)(tab + (((unsigned)node << 5) | pof));
            ACC8(A, su);
        }
        for (; j + 3 < e; j += 4) {
            int i0 = csr[j], i1 = csr[j + 1], i2 = csr[j + 2], i3 = csr[j + 3];
            uint4 u0 = *(const uint4*)(tab + (((unsigned)i0 << 5) | pof));
            uint4 u1 = *(const uint4*)(tab + (((unsigned)i1 << 5) | pof));
            uint4 u2 = *(const uint4*)(tab + (((unsigned)i2 << 5) | pof));
            uint4 u3 = *(const uint4*)(tab + (((unsigned)i3 << 5) | pof));
            ACC8(A, u0); ACC8(B, u1); ACC8(A, u2); ACC8(B, u3);
        }
        for (; j < e; ++j) {
            uint4 u = *(const uint4*)(tab + (((unsigned)csr[j] << 5) | pof));
            ACC8(A, u);
        }
        float v[8];
        #pragma unroll
        for (int k = 0; k < 8; ++k) v[k] = A[k] + B[k];
        #pragma unroll
        for (int k = 0; k < 8; ++k) {
            v[k] += __shfl_xor(v[k], 2, 64);
            v[k] += __shfl_xor(v[k], 4, 64);
        }
        if (seg == 0) {
            float di = dinv[node];
            #pragma unroll
            for (int k = 0; k < 8; ++k) agg[g][8 * p + k] = v[k] * di;
        }
    }
    __syncthreads();

    int wav = threadIdx.x >> 6, lane = threadIdx.x & 63;
    int nbase = blockIdx.x * 32 + wav * 8;
    #pragma unroll
    for (int q = 0; q < 8; ++q) {
        int nd = nbase + q;
        if (nd >= n) break;  // nd uniform across wave
        float av[16];
        #pragma unroll
        for (int k = 0; k < 16; ++k) av[k] = agg[wav * 8 + q][k];
        float d = -1e30f;
        if (lane < NF2) {
            d = b2s[lane];
            #pragma unroll
            for (int k = 0; k < 16; ++k) d = fmaf(av[k], w2s[k * NF2 + lane], d);
        }
        float m = d;
        #pragma unroll
        for (int off = 32; off; off >>= 1) m = fmaxf(m, __shfl_xor(m, off, 64));
        float e2 = (lane < NF2) ? __expf(d - m) : 0.f;
        float ssum = e2;
        #pragma unroll
        for (int off = 32; off; off >>= 1) ssum += __shfl_xor(ssum, off, 64);
        float ls = __logf(ssum);
        if (lane < NF2) out[(size_t)nd * NF2 + lane] = d - m - ls;
    }
}

// ---------------- launch ----------------

extern "C" void kernel_launch(void* const* d_in, const int* in_sizes, int n_in,
                              void* d_out, int out_size, void* d_ws, size_t ws_size,
                              hipStream_t stream) {
    const float* x  = (const float*)d_in[0];
    const int*   ei = (const int*)d_in[1];
    const float* W1 = (const float*)d_in[2];
    const float* b1 = (const float*)d_in[3];
    const float* W2 = (const float*)d_in[4];
    const float* b2 = (const float*)d_in[5];
    float* out = (float*)d_out;

    const int N = in_sizes[0] / NF0;  // 100000
    const int E = in_sizes[1] / 2;    // 3200000
    const int NB = (N + BNODES - 1) / BNODES;  // 782
    const int* src = ei;
    const int* dst = ei + E;

    char* ws = (char*)d_ws;
    size_t off = 0;
    auto alloc = [&](size_t bytes) -> void* {
        void* p = ws + off;
        off = (off + bytes + 255) & ~(size_t)255;
        return p;
    };
    int*   cursor = (int*)alloc((size_t)NB * 4);
    unsigned int* binned = (unsigned int*)alloc((size_t)NB * MAXPB * 4);
    int*   csr    = (int*)alloc((size_t)NB * MAXPB * 4);
    int2*  oe     = (int2*)alloc((size_t)N * 8);
    float* dinv   = (float*)alloc((size_t)N * 4);
    float* h1f    = (float*)alloc((size_t)N * 16 * 4);   // unscaled fp32 GEMM out
    unsigned int* h1s = (unsigned int*)alloc((size_t)N * 8 * 4);  // scaled bf16 table
    // binned dead after k_build: reuse for bf16 hs2 (3.2MB)
    unsigned int* hs2 = binned;

    const int SORTB = (E + CHUNK - 1) / CHUNK;  // 391
    const int NGEMM = 1024;
    const int gblocks = (N * 8 + 255) / 256;    // 8 lanes/node

    k_zero    <<<(NB + 255) / 256, 256, 0, stream>>>(cursor, NB);
    k_sortgemm<<<SORTB + NGEMM, 256, 0, stream>>>(src, dst, cursor, binned,
                                                  x, W1, h1f, E, NB, SORTB, N);
    k_build   <<<NB, 256, 0, stream>>>(binned, cursor, csr, oe, dinv,
                                       h1f, (uint4*)h1s, N);
    k_gather1 <<<gblocks, 256, 0, stream>>>(oe, csr, (const uint4*)h1s, dinv, b1,
                                            (uint4*)hs2, N);
    k_g2f     <<<gblocks, 256, 0, stream>>>(oe, csr, (const uint4*)hs2, dinv, W2, b2,
                                            out, N);
}